// Round 3
// baseline (596.951 us; speedup 1.0000x reference)
//
#include <hip/hip_runtime.h>
#include <math.h>

#define N_NODES 100000   // 4 * 25000
#define N_EDGES 1000000
// IN=64, TD=64, OUT=64, H=4, HD=16

// ---------------------------------------------------------------------------
// Kernel 1: Q/K/V projections, register-tiled (unchanged from round 2).
// ---------------------------------------------------------------------------
__global__ __launch_bounds__(256) void qkv_kernel(
    const float* __restrict__ x, const float* __restrict__ tf,
    const float* __restrict__ qw, const float* __restrict__ qb,
    const float* __restrict__ kw, const float* __restrict__ kb,
    const float* __restrict__ vw, const float* __restrict__ vb,
    float* __restrict__ Q, float* __restrict__ K, float* __restrict__ V)
{
    __shared__ float xt[32][128];
    const int t = threadIdx.x;
    const int base = blockIdx.x * 32;

    #pragma unroll
    for (int m = 0; m < 8; ++m) {
        const int k = t + m * 256;          // 0..2047
        const int n = k >> 6, j = k & 63;
        xt[n][j]      = x [(size_t)(base + n) * 64 + j];
        xt[n][64 + j] = tf[(size_t)(base + n) * 64 + j];
    }
    __syncthreads();

    const int g = t >> 6;      // wave group: nodes g*8 .. g*8+7
    const int c = t & 63;      // output column

    float qa[8], ka[8], va[8];
    #pragma unroll
    for (int n = 0; n < 8; ++n) { qa[n] = qb[c]; ka[n] = kb[c]; va[n] = vb[c]; }

    #pragma unroll 4
    for (int i = 0; i < 128; ++i) {
        const float qwv = qw[i * 64 + c];
        const float kwv = kw[i * 64 + c];
        #pragma unroll
        for (int n = 0; n < 8; ++n) {
            const float xv = xt[g * 8 + n][i];
            qa[n] = fmaf(xv, qwv, qa[n]);
            ka[n] = fmaf(xv, kwv, ka[n]);
        }
    }
    #pragma unroll 4
    for (int i = 0; i < 64; ++i) {
        const float vwv = vw[i * 64 + c];
        #pragma unroll
        for (int n = 0; n < 8; ++n)
            va[n] = fmaf(xt[g * 8 + n][i], vwv, va[n]);
    }

    #pragma unroll
    for (int n = 0; n < 8; ++n) {
        const size_t o = (size_t)(base + g * 8 + n) * 64 + c;
        Q[o] = qa[n]; K[o] = ka[n]; V[o] = va[n];
    }
}

// ---------------------------------------------------------------------------
// CSR build: degree count -> exclusive scan -> fill (src ids grouped by dst)
// ---------------------------------------------------------------------------
__global__ __launch_bounds__(256) void deg_kernel(
    const int* __restrict__ dst, int* __restrict__ deg)
{
    const int e = blockIdx.x * 256 + threadIdx.x;
    if (e < N_EDGES) atomicAdd(&deg[dst[e]], 1);
}

// single block, 1024 threads: serial chunk sums -> LDS scan -> write offsets
__global__ __launch_bounds__(1024) void scan_kernel(
    const int* __restrict__ deg, int* __restrict__ off, int* __restrict__ cursor)
{
    __shared__ int tsum[1024];
    const int t = threadIdx.x;
    const int chunk = (N_NODES + 1023) / 1024;      // 98
    const int lo = t * chunk;
    const int hi = (lo + chunk < N_NODES) ? lo + chunk : N_NODES;

    int s = 0;
    for (int i = lo; i < hi; ++i) s += deg[i];
    tsum[t] = s;
    __syncthreads();

    // Hillis-Steele inclusive scan over 1024 thread sums
    for (int d = 1; d < 1024; d <<= 1) {
        const int v = (t >= d) ? tsum[t - d] : 0;
        __syncthreads();
        tsum[t] += v;
        __syncthreads();
    }

    int run = tsum[t] - s;                          // exclusive prefix
    for (int i = lo; i < hi; ++i) {
        off[i] = run; cursor[i] = run; run += deg[i];
    }
    if (t == 1023) off[N_NODES] = run;              // thread 1023's chunk is empty
}

__global__ __launch_bounds__(256) void fill_kernel(
    const int* __restrict__ src, const int* __restrict__ dst,
    int* __restrict__ cursor, int* __restrict__ csr_src)
{
    const int e = blockIdx.x * 256 + threadIdx.x;
    if (e < N_EDGES) {
        const int pos = atomicAdd(&cursor[dst[e]], 1);
        csr_src[pos] = src[e];
    }
}

// ---------------------------------------------------------------------------
// Kernel 5: gather-aggregate + normalize + output GEMM, fused.
// One wave per dst node (4 nodes / block). lane = h*16 + d holds one column.
// Per edge: gather K,V rows, 16-lane dot reduce, p=exp(score), accumulate in
// registers. No value atomics anywhere. Then agg -> LDS -> 64x64 GEMM + bias.
// ---------------------------------------------------------------------------
__global__ __launch_bounds__(256) void agg_kernel(
    const int* __restrict__ off, const int* __restrict__ csr_src,
    const float* __restrict__ Q, const float* __restrict__ K,
    const float* __restrict__ V,
    const float* __restrict__ ow, const float* __restrict__ ob,
    float* __restrict__ out)
{
    __shared__ float agg[4][64];
    const int wave = threadIdx.x >> 6;
    const int lane = threadIdx.x & 63;
    const int node = blockIdx.x * 4 + wave;         // grid exact: 25000*4

    const float q = Q[(size_t)node * 64 + lane];
    const int lo = off[node], hi = off[node + 1];

    float acc = 0.0f, ssum = 0.0f;
    for (int i = lo; i < hi; ++i) {
        const int s = csr_src[i];
        float prod = q * K[(size_t)s * 64 + lane];
        prod += __shfl_xor(prod, 1);
        prod += __shfl_xor(prod, 2);
        prod += __shfl_xor(prod, 4);
        prod += __shfl_xor(prod, 8);                // every lane has head sum
        const float p = __expf(prod * 0.25f);       // 1/sqrt(16)
        ssum += p;
        acc = fmaf(p, V[(size_t)s * 64 + lane], acc);
    }
    agg[wave][lane] = (ssum > 0.0f) ? (acc / ssum) : 0.0f;
    __syncthreads();

    float o = ob[lane];
    #pragma unroll 8
    for (int i = 0; i < 64; ++i)
        o = fmaf(agg[wave][i], ow[i * 64 + lane], o);
    out[(size_t)node * 64 + lane] = o;
}

// ---------------------------------------------------------------------------
extern "C" void kernel_launch(void* const* d_in, const int* in_sizes, int n_in,
                              void* d_out, int out_size, void* d_ws, size_t ws_size,
                              hipStream_t stream) {
    const float* x  = (const float*)d_in[0];
    const float* tf = (const float*)d_in[1];
    const int*   ei = (const int*)  d_in[2];
    const float* qw = (const float*)d_in[3];
    const float* qb = (const float*)d_in[4];
    const float* kw = (const float*)d_in[5];
    const float* kb = (const float*)d_in[6];
    const float* vw = (const float*)d_in[7];
    const float* vb = (const float*)d_in[8];
    const float* ow = (const float*)d_in[9];
    const float* ob = (const float*)d_in[10];
    float* out = (float*)d_out;

    char* ws = (char*)d_ws;
    const size_t nf = (size_t)N_NODES * 64 * sizeof(float);   // 25.6 MB

    float* Q       = (float*)(ws);
    float* K       = (float*)(ws + nf);
    float* V       = (float*)(ws + 2 * nf);
    int*   deg     = (int*)(ws + 3 * nf);
    int*   off     = deg + N_NODES;          // N+1 entries
    int*   cursor  = off + N_NODES + 1;
    int*   csr_src = cursor + N_NODES;

    const int* src = ei;             // edge_index[0]
    const int* dst = ei + N_EDGES;   // edge_index[1]

    hipMemsetAsync(deg, 0, N_NODES * sizeof(int), stream);

    const dim3 blk(256);
    qkv_kernel<<<dim3(N_NODES / 32), blk, 0, stream>>>(
        x, tf, qw, qb, kw, kb, vw, vb, Q, K, V);

    const int eb = (N_EDGES + 255) / 256;
    deg_kernel <<<dim3(eb), blk, 0, stream>>>(dst, deg);
    scan_kernel<<<dim3(1), dim3(1024), 0, stream>>>(deg, off, cursor);
    fill_kernel<<<dim3(eb), blk, 0, stream>>>(src, dst, cursor, csr_src);

    agg_kernel<<<dim3(N_NODES / 4), blk, 0, stream>>>(
        off, csr_src, Q, K, V, ow, ob, out);
}

// Round 4
// 375.003 us; speedup vs baseline: 1.5919x; 1.5919x over previous
//
#include <hip/hip_runtime.h>
#include <math.h>

#define N_NODES 100000   // 4 * 25000
#define N_EDGES 1000000
#define SCAN_BLOCKS ((N_NODES + 255) / 256)   // 391
// IN=64, TD=64, OUT=64, H=4, HD=16

// ---------------------------------------------------------------------------
// Kernel 1: Q/K/V projections, register-tiled.
// ---------------------------------------------------------------------------
__global__ __launch_bounds__(256) void qkv_kernel(
    const float* __restrict__ x, const float* __restrict__ tf,
    const float* __restrict__ qw, const float* __restrict__ qb,
    const float* __restrict__ kw, const float* __restrict__ kb,
    const float* __restrict__ vw, const float* __restrict__ vb,
    float* __restrict__ Q, float* __restrict__ K, float* __restrict__ V)
{
    __shared__ float xt[32][128];
    const int t = threadIdx.x;
    const int base = blockIdx.x * 32;

    #pragma unroll
    for (int m = 0; m < 8; ++m) {
        const int k = t + m * 256;          // 0..2047
        const int n = k >> 6, j = k & 63;
        xt[n][j]      = x [(size_t)(base + n) * 64 + j];
        xt[n][64 + j] = tf[(size_t)(base + n) * 64 + j];
    }
    __syncthreads();

    const int g = t >> 6;      // wave group: nodes g*8 .. g*8+7
    const int c = t & 63;      // output column

    float qa[8], ka[8], va[8];
    #pragma unroll
    for (int n = 0; n < 8; ++n) { qa[n] = qb[c]; ka[n] = kb[c]; va[n] = vb[c]; }

    #pragma unroll 4
    for (int i = 0; i < 128; ++i) {
        const float qwv = qw[i * 64 + c];
        const float kwv = kw[i * 64 + c];
        #pragma unroll
        for (int n = 0; n < 8; ++n) {
            const float xv = xt[g * 8 + n][i];
            qa[n] = fmaf(xv, qwv, qa[n]);
            ka[n] = fmaf(xv, kwv, ka[n]);
        }
    }
    #pragma unroll 4
    for (int i = 0; i < 64; ++i) {
        const float vwv = vw[i * 64 + c];
        #pragma unroll
        for (int n = 0; n < 8; ++n)
            va[n] = fmaf(xt[g * 8 + n][i], vwv, va[n]);
    }

    #pragma unroll
    for (int n = 0; n < 8; ++n) {
        const size_t o = (size_t)(base + g * 8 + n) * 64 + c;
        Q[o] = qa[n]; K[o] = ka[n]; V[o] = va[n];
    }
}

// ---------------------------------------------------------------------------
// CSR build: degree count -> multi-block exclusive scan -> fill
// ---------------------------------------------------------------------------
__global__ __launch_bounds__(256) void deg_kernel(
    const int* __restrict__ dst, int* __restrict__ deg)
{
    const int e = blockIdx.x * 256 + threadIdx.x;
    if (e < N_EDGES) atomicAdd(&deg[dst[e]], 1);
}

// Stage A: per-block sums of deg (391 blocks)
__global__ __launch_bounds__(256) void blocksum_kernel(
    const int* __restrict__ deg, int* __restrict__ bsum)
{
    __shared__ int red[256];
    const int t = threadIdx.x;
    const int i = blockIdx.x * 256 + t;
    red[t] = (i < N_NODES) ? deg[i] : 0;
    __syncthreads();
    #pragma unroll
    for (int d = 128; d > 0; d >>= 1) {
        if (t < d) red[t] += red[t + d];
        __syncthreads();
    }
    if (t == 0) bsum[blockIdx.x] = red[0];
}

// Stage B: single small block scans the 391 block sums (exclusive)
__global__ __launch_bounds__(512) void blockscan_kernel(
    const int* __restrict__ bsum, int* __restrict__ bbase)
{
    __shared__ int s[512];
    const int t = threadIdx.x;
    const int v = (t < SCAN_BLOCKS) ? bsum[t] : 0;
    s[t] = v;
    __syncthreads();
    for (int d = 1; d < 512; d <<= 1) {
        const int u = (t >= d) ? s[t - d] : 0;
        __syncthreads();
        s[t] += u;
        __syncthreads();
    }
    if (t < SCAN_BLOCKS) bbase[t] = s[t] - v;   // exclusive prefix
}

// Stage C: per-block LDS scan + block base -> off / cursor
__global__ __launch_bounds__(256) void offsets_kernel(
    const int* __restrict__ deg, const int* __restrict__ bbase,
    int* __restrict__ off, int* __restrict__ cursor)
{
    __shared__ int s[256];
    const int t = threadIdx.x;
    const int i = blockIdx.x * 256 + t;
    const int v = (i < N_NODES) ? deg[i] : 0;
    s[t] = v;
    __syncthreads();
    for (int d = 1; d < 256; d <<= 1) {
        const int u = (t >= d) ? s[t - d] : 0;
        __syncthreads();
        s[t] += u;
        __syncthreads();
    }
    const int incl = s[t];
    const int base = bbase[blockIdx.x];
    if (i < N_NODES) {
        const int ex = base + incl - v;
        off[i] = ex;
        cursor[i] = ex;
        if (i == N_NODES - 1) off[N_NODES] = base + incl;
    }
}

__global__ __launch_bounds__(256) void fill_kernel(
    const int* __restrict__ src, const int* __restrict__ dst,
    int* __restrict__ cursor, int* __restrict__ csr_src)
{
    const int e = blockIdx.x * 256 + threadIdx.x;
    if (e < N_EDGES) {
        const int pos = atomicAdd(&cursor[dst[e]], 1);
        csr_src[pos] = src[e];
    }
}

// ---------------------------------------------------------------------------
// Gather-aggregate + normalize + output GEMM, fused. One wave per dst node.
// Software-pipelined edge loop: next edge's csr/K/V loads overlap current
// edge's reduce+exp+fma.
// ---------------------------------------------------------------------------
__global__ __launch_bounds__(256) void agg_kernel(
    const int* __restrict__ off, const int* __restrict__ csr_src,
    const float* __restrict__ Q, const float* __restrict__ K,
    const float* __restrict__ V,
    const float* __restrict__ ow, const float* __restrict__ ob,
    float* __restrict__ out)
{
    __shared__ float agg[4][64];
    const int wave = threadIdx.x >> 6;
    const int lane = threadIdx.x & 63;
    const int node = blockIdx.x * 4 + wave;         // grid exact: 25000*4

    const float q = Q[(size_t)node * 64 + lane];
    const int lo = off[node], hi = off[node + 1];

    float acc = 0.0f, ssum = 0.0f;
    if (lo < hi) {
        int s = csr_src[lo];
        float kv = K[(size_t)s * 64 + lane];
        float vv = V[(size_t)s * 64 + lane];
        for (int i = lo; i < hi; ++i) {
            float kn = 0.0f, vn = 0.0f;
            if (i + 1 < hi) {                        // prefetch next edge
                const int sn = csr_src[i + 1];
                kn = K[(size_t)sn * 64 + lane];
                vn = V[(size_t)sn * 64 + lane];
            }
            float prod = q * kv;
            prod += __shfl_xor(prod, 1);
            prod += __shfl_xor(prod, 2);
            prod += __shfl_xor(prod, 4);
            prod += __shfl_xor(prod, 8);             // head-group sum
            const float p = __expf(prod * 0.25f);    // 1/sqrt(16)
            ssum += p;
            acc = fmaf(p, vv, acc);
            kv = kn; vv = vn;
        }
    }
    agg[wave][lane] = (ssum > 0.0f) ? (acc / ssum) : 0.0f;
    __syncthreads();

    float o = ob[lane];
    #pragma unroll 8
    for (int i = 0; i < 64; ++i)
        o = fmaf(agg[wave][i], ow[i * 64 + lane], o);
    out[(size_t)node * 64 + lane] = o;
}

// ---------------------------------------------------------------------------
extern "C" void kernel_launch(void* const* d_in, const int* in_sizes, int n_in,
                              void* d_out, int out_size, void* d_ws, size_t ws_size,
                              hipStream_t stream) {
    const float* x  = (const float*)d_in[0];
    const float* tf = (const float*)d_in[1];
    const int*   ei = (const int*)  d_in[2];
    const float* qw = (const float*)d_in[3];
    const float* qb = (const float*)d_in[4];
    const float* kw = (const float*)d_in[5];
    const float* kb = (const float*)d_in[6];
    const float* vw = (const float*)d_in[7];
    const float* vb = (const float*)d_in[8];
    const float* ow = (const float*)d_in[9];
    const float* ob = (const float*)d_in[10];
    float* out = (float*)d_out;

    char* ws = (char*)d_ws;
    const size_t nf = (size_t)N_NODES * 64 * sizeof(float);   // 25.6 MB

    float* Q       = (float*)(ws);
    float* K       = (float*)(ws + nf);
    float* V       = (float*)(ws + 2 * nf);
    int*   deg     = (int*)(ws + 3 * nf);
    int*   off     = deg + N_NODES;              // N+1 entries
    int*   cursor  = off + N_NODES + 1;
    int*   csr_src = cursor + N_NODES;
    int*   bsum    = csr_src + N_EDGES;
    int*   bbase   = bsum + SCAN_BLOCKS;

    const int* src = ei;             // edge_index[0]
    const int* dst = ei + N_EDGES;   // edge_index[1]

    hipMemsetAsync(deg, 0, N_NODES * sizeof(int), stream);

    const dim3 blk(256);
    qkv_kernel<<<dim3(N_NODES / 32), blk, 0, stream>>>(
        x, tf, qw, qb, kw, kb, vw, vb, Q, K, V);

    const int eb = (N_EDGES + 255) / 256;
    deg_kernel      <<<dim3(eb), blk, 0, stream>>>(dst, deg);
    blocksum_kernel <<<dim3(SCAN_BLOCKS), blk, 0, stream>>>(deg, bsum);
    blockscan_kernel<<<dim3(1), dim3(512), 0, stream>>>(bsum, bbase);
    offsets_kernel  <<<dim3(SCAN_BLOCKS), blk, 0, stream>>>(deg, bbase, off, cursor);
    fill_kernel     <<<dim3(eb), blk, 0, stream>>>(src, dst, cursor, csr_src);

    agg_kernel<<<dim3(N_NODES / 4), blk, 0, stream>>>(
        off, csr_src, Q, K, V, ow, ob, out);
}

// Round 5
// 299.011 us; speedup vs baseline: 1.9964x; 1.2541x over previous
//
#include <hip/hip_runtime.h>
#include <math.h>

#define N_NODES 100000   // 4 * 25000
#define N_EDGES 1000000
#define SCAN_BLOCKS ((N_NODES + 255) / 256)   // 391
// IN=64, TD=64, OUT=64, H=4, HD=16

// ---------------------------------------------------------------------------
// Kernel 1: Q/K/V projections, register-tiled.
// ---------------------------------------------------------------------------
__global__ __launch_bounds__(256) void qkv_kernel(
    const float* __restrict__ x, const float* __restrict__ tf,
    const float* __restrict__ qw, const float* __restrict__ qb,
    const float* __restrict__ kw, const float* __restrict__ kb,
    const float* __restrict__ vw, const float* __restrict__ vb,
    float* __restrict__ Q, float* __restrict__ K, float* __restrict__ V)
{
    __shared__ float xt[32][128];
    const int t = threadIdx.x;
    const int base = blockIdx.x * 32;

    #pragma unroll
    for (int m = 0; m < 8; ++m) {
        const int k = t + m * 256;          // 0..2047
        const int n = k >> 6, j = k & 63;
        xt[n][j]      = x [(size_t)(base + n) * 64 + j];
        xt[n][64 + j] = tf[(size_t)(base + n) * 64 + j];
    }
    __syncthreads();

    const int g = t >> 6;      // wave group: nodes g*8 .. g*8+7
    const int c = t & 63;      // output column

    float qa[8], ka[8], va[8];
    #pragma unroll
    for (int n = 0; n < 8; ++n) { qa[n] = qb[c]; ka[n] = kb[c]; va[n] = vb[c]; }

    #pragma unroll 4
    for (int i = 0; i < 128; ++i) {
        const float qwv = qw[i * 64 + c];
        const float kwv = kw[i * 64 + c];
        #pragma unroll
        for (int n = 0; n < 8; ++n) {
            const float xv = xt[g * 8 + n][i];
            qa[n] = fmaf(xv, qwv, qa[n]);
            ka[n] = fmaf(xv, kwv, ka[n]);
        }
    }
    #pragma unroll 4
    for (int i = 0; i < 64; ++i) {
        const float vwv = vw[i * 64 + c];
        #pragma unroll
        for (int n = 0; n < 8; ++n)
            va[n] = fmaf(xt[g * 8 + n][i], vwv, va[n]);
    }

    #pragma unroll
    for (int n = 0; n < 8; ++n) {
        const size_t o = (size_t)(base + g * 8 + n) * 64 + c;
        Q[o] = qa[n]; K[o] = ka[n]; V[o] = va[n];
    }
}

// ---------------------------------------------------------------------------
// CSR build: degree count -> multi-block exclusive scan -> fill
// ---------------------------------------------------------------------------
__global__ __launch_bounds__(256) void deg_kernel(
    const int* __restrict__ dst, int* __restrict__ deg)
{
    const int e = blockIdx.x * 256 + threadIdx.x;
    if (e < N_EDGES) atomicAdd(&deg[dst[e]], 1);
}

__global__ __launch_bounds__(256) void blocksum_kernel(
    const int* __restrict__ deg, int* __restrict__ bsum)
{
    __shared__ int red[256];
    const int t = threadIdx.x;
    const int i = blockIdx.x * 256 + t;
    red[t] = (i < N_NODES) ? deg[i] : 0;
    __syncthreads();
    #pragma unroll
    for (int d = 128; d > 0; d >>= 1) {
        if (t < d) red[t] += red[t + d];
        __syncthreads();
    }
    if (t == 0) bsum[blockIdx.x] = red[0];
}

__global__ __launch_bounds__(512) void blockscan_kernel(
    const int* __restrict__ bsum, int* __restrict__ bbase)
{
    __shared__ int s[512];
    const int t = threadIdx.x;
    const int v = (t < SCAN_BLOCKS) ? bsum[t] : 0;
    s[t] = v;
    __syncthreads();
    for (int d = 1; d < 512; d <<= 1) {
        const int u = (t >= d) ? s[t - d] : 0;
        __syncthreads();
        s[t] += u;
        __syncthreads();
    }
    if (t < SCAN_BLOCKS) bbase[t] = s[t] - v;   // exclusive prefix
}

__global__ __launch_bounds__(256) void offsets_kernel(
    const int* __restrict__ deg, const int* __restrict__ bbase,
    int* __restrict__ off, int* __restrict__ cursor)
{
    __shared__ int s[256];
    const int t = threadIdx.x;
    const int i = blockIdx.x * 256 + t;
    const int v = (i < N_NODES) ? deg[i] : 0;
    s[t] = v;
    __syncthreads();
    for (int d = 1; d < 256; d <<= 1) {
        const int u = (t >= d) ? s[t - d] : 0;
        __syncthreads();
        s[t] += u;
        __syncthreads();
    }
    const int incl = s[t];
    const int base = bbase[blockIdx.x];
    if (i < N_NODES) {
        const int ex = base + incl - v;
        off[i] = ex;
        cursor[i] = ex;
        if (i == N_NODES - 1) off[N_NODES] = base + incl;
    }
}

__global__ __launch_bounds__(256) void fill_kernel(
    const int* __restrict__ src, const int* __restrict__ dst,
    int* __restrict__ cursor, int* __restrict__ csr_src)
{
    const int e = blockIdx.x * 256 + threadIdx.x;
    if (e < N_EDGES) {
        const int pos = atomicAdd(&cursor[dst[e]], 1);
        csr_src[pos] = src[e];
    }
}

// ---------------------------------------------------------------------------
// Gather-aggregate + normalize + output GEMM, fused. One wave per dst node,
// FOUR edges per iteration: lane = (slot g = lane>>4) * 16 + (sublane s),
// sublane s holds columns 4s..4s+3 as float4. Head of those cols = s>>2.
// Per iteration: 1 csr load + 2 dwordx4 gathers per lane; 2 shfl_xor reduce
// all 4 edge dots at once; 1 exp serves 16 (edge,head) pairs.
// ---------------------------------------------------------------------------
__global__ __launch_bounds__(256) void agg_kernel(
    const int* __restrict__ off, const int* __restrict__ csr_src,
    const float* __restrict__ Q, const float* __restrict__ K,
    const float* __restrict__ V,
    const float* __restrict__ ow, const float* __restrict__ ob,
    float* __restrict__ out)
{
    __shared__ float agg[4][64];
    const int wave = threadIdx.x >> 6;
    const int lane = threadIdx.x & 63;
    const int g    = lane >> 4;        // edge slot 0..3
    const int s    = lane & 15;        // sublane: columns 4s..4s+3
    const int node = blockIdx.x * 4 + wave;   // grid exact: 25000*4

    const float4* __restrict__ K4 = (const float4*)K;
    const float4* __restrict__ V4 = (const float4*)V;
    const float4* __restrict__ Q4 = (const float4*)Q;

    const float4 q4 = Q4[(size_t)node * 16 + s];
    const int lo = off[node], hi = off[node + 1];

    float ax = 0.f, ay = 0.f, az = 0.f, aw = 0.f, ssum = 0.f;

    if (lo < hi) {
        int base = lo;
        const int e0 = base + g;
        const int i0 = csr_src[(e0 < hi) ? e0 : (hi - 1)];
        bool  act = (e0 < hi);
        float4 k4 = K4[(size_t)i0 * 16 + s];
        float4 v4 = V4[(size_t)i0 * 16 + s];

        while (base < hi) {
            const int nbase = base + 4;
            float4 kn = make_float4(0.f, 0.f, 0.f, 0.f);
            float4 vn = make_float4(0.f, 0.f, 0.f, 0.f);
            bool actn = false;
            if (nbase < hi) {                     // prefetch next 4-edge batch
                const int en = nbase + g;
                const int in = csr_src[(en < hi) ? en : (hi - 1)];
                kn = K4[(size_t)in * 16 + s];
                vn = V4[(size_t)in * 16 + s];
                actn = (en < hi);
            }
            float d = q4.x * k4.x + q4.y * k4.y + q4.z * k4.z + q4.w * k4.w;
            d += __shfl_xor(d, 1);
            d += __shfl_xor(d, 2);                // full 16-dim head dot
            const float p = act ? __expf(d * 0.25f) : 0.0f;   // 1/sqrt(16)
            ssum += p;
            ax = fmaf(p, v4.x, ax); ay = fmaf(p, v4.y, ay);
            az = fmaf(p, v4.z, az); aw = fmaf(p, v4.w, aw);
            k4 = kn; v4 = vn; act = actn;
            base = nbase;
        }
    }

    // combine the 4 edge slots (bits 4,5 of lane)
    ax += __shfl_xor(ax, 16);  ax += __shfl_xor(ax, 32);
    ay += __shfl_xor(ay, 16);  ay += __shfl_xor(ay, 32);
    az += __shfl_xor(az, 16);  az += __shfl_xor(az, 32);
    aw += __shfl_xor(aw, 16);  aw += __shfl_xor(aw, 32);
    ssum += __shfl_xor(ssum, 16);  ssum += __shfl_xor(ssum, 32);

    const float inv = (ssum > 0.f) ? (1.0f / ssum) : 0.0f;
    if (g == 0) {
        agg[wave][4 * s + 0] = ax * inv;
        agg[wave][4 * s + 1] = ay * inv;
        agg[wave][4 * s + 2] = az * inv;
        agg[wave][4 * s + 3] = aw * inv;
    }
    __syncthreads();

    float o = ob[lane];
    #pragma unroll 8
    for (int i = 0; i < 64; ++i)
        o = fmaf(agg[wave][i], ow[i * 64 + lane], o);
    out[(size_t)node * 64 + lane] = o;
}

// ---------------------------------------------------------------------------
extern "C" void kernel_launch(void* const* d_in, const int* in_sizes, int n_in,
                              void* d_out, int out_size, void* d_ws, size_t ws_size,
                              hipStream_t stream) {
    const float* x  = (const float*)d_in[0];
    const float* tf = (const float*)d_in[1];
    const int*   ei = (const int*)  d_in[2];
    const float* qw = (const float*)d_in[3];
    const float* qb = (const float*)d_in[4];
    const float* kw = (const float*)d_in[5];
    const float* kb = (const float*)d_in[6];
    const float* vw = (const float*)d_in[7];
    const float* vb = (const float*)d_in[8];
    const float* ow = (const float*)d_in[9];
    const float* ob = (const float*)d_in[10];
    float* out = (float*)d_out;

    char* ws = (char*)d_ws;
    const size_t nf = (size_t)N_NODES * 64 * sizeof(float);   // 25.6 MB

    float* Q       = (float*)(ws);
    float* K       = (float*)(ws + nf);
    float* V       = (float*)(ws + 2 * nf);
    int*   deg     = (int*)(ws + 3 * nf);
    int*   off     = deg + N_NODES;              // N+1 entries
    int*   cursor  = off + N_NODES + 1;
    int*   csr_src = cursor + N_NODES;
    int*   bsum    = csr_src + N_EDGES;
    int*   bbase   = bsum + SCAN_BLOCKS;

    const int* src = ei;             // edge_index[0]
    const int* dst = ei + N_EDGES;   // edge_index[1]

    hipMemsetAsync(deg, 0, N_NODES * sizeof(int), stream);

    const dim3 blk(256);
    qkv_kernel<<<dim3(N_NODES / 32), blk, 0, stream>>>(
        x, tf, qw, qb, kw, kb, vw, vb, Q, K, V);

    const int eb = (N_EDGES + 255) / 256;
    deg_kernel      <<<dim3(eb), blk, 0, stream>>>(dst, deg);
    blocksum_kernel <<<dim3(SCAN_BLOCKS), blk, 0, stream>>>(deg, bsum);
    blockscan_kernel<<<dim3(1), dim3(512), 0, stream>>>(bsum, bbase);
    offsets_kernel  <<<dim3(SCAN_BLOCKS), blk, 0, stream>>>(deg, bbase, off, cursor);
    fill_kernel     <<<dim3(eb), blk, 0, stream>>>(src, dst, cursor, csr_src);

    agg_kernel<<<dim3(N_NODES / 4), blk, 0, stream>>>(
        off, csr_src, Q, K, V, ow, ob, out);
}

// Round 6
// 264.224 us; speedup vs baseline: 2.2593x; 1.1317x over previous
//
#include <hip/hip_runtime.h>
#include <hip/hip_fp16.h>
#include <math.h>

#define N_NODES 100000   // 4 * 25000 ; 32 * 3125
#define N_EDGES 1000000
#define QKV_BLOCKS (N_NODES / 32)             // 3125
#define SC_BLOCKS  ((N_NODES + 255) / 256)    // 391
// IN=64, TD=64, OUT=64, H=4, HD=16

// ---------------------------------------------------------------------------
// Kernel 1: Q/K/V projections (register-tiled) + fused degree count.
// K/V stored as fp16 (halves agg's gather traffic). Q stays f32.
// ---------------------------------------------------------------------------
__global__ __launch_bounds__(256) void qkv_deg_kernel(
    const float* __restrict__ x, const float* __restrict__ tf,
    const float* __restrict__ qw, const float* __restrict__ qb,
    const float* __restrict__ kw, const float* __restrict__ kb,
    const float* __restrict__ vw, const float* __restrict__ vb,
    const int* __restrict__ dst, int* __restrict__ deg,
    float* __restrict__ Q, __half* __restrict__ Kh, __half* __restrict__ Vh)
{
    __shared__ float xt[32][128];
    const int t = threadIdx.x;
    const int base = blockIdx.x * 32;

    #pragma unroll
    for (int m = 0; m < 8; ++m) {
        const int k = t + m * 256;          // 0..2047
        const int n = k >> 6, j = k & 63;
        xt[n][j]      = x [(size_t)(base + n) * 64 + j];
        xt[n][64 + j] = tf[(size_t)(base + n) * 64 + j];
    }
    __syncthreads();

    const int g = t >> 6;      // wave group: nodes g*8 .. g*8+7
    const int c = t & 63;      // output column

    float qa[8], ka[8], va[8];
    #pragma unroll
    for (int n = 0; n < 8; ++n) { qa[n] = qb[c]; ka[n] = kb[c]; va[n] = vb[c]; }

    #pragma unroll 4
    for (int i = 0; i < 128; ++i) {
        const float qwv = qw[i * 64 + c];
        const float kwv = kw[i * 64 + c];
        #pragma unroll
        for (int n = 0; n < 8; ++n) {
            const float xv = xt[g * 8 + n][i];
            qa[n] = fmaf(xv, qwv, qa[n]);
            ka[n] = fmaf(xv, kwv, ka[n]);
        }
    }
    #pragma unroll 4
    for (int i = 0; i < 64; ++i) {
        const float vwv = vw[i * 64 + c];
        #pragma unroll
        for (int n = 0; n < 8; ++n)
            va[n] = fmaf(xt[g * 8 + n][i], vwv, va[n]);
    }

    #pragma unroll
    for (int n = 0; n < 8; ++n) {
        const size_t o = (size_t)(base + g * 8 + n) * 64 + c;
        Q [o] = qa[n];
        Kh[o] = __float2half(ka[n]);
        Vh[o] = __float2half(va[n]);
    }

    // fused degree count (grid-stride over edges; <=2 atomics per thread)
    const int tid = blockIdx.x * 256 + t;
    for (int e = tid; e < N_EDGES; e += QKV_BLOCKS * 256)
        atomicAdd(&deg[dst[e]], 1);
}

// ---------------------------------------------------------------------------
// CSR ranges: per-block LDS scan + atomic global base. Ranges are disjoint
// but not globally ordered (agg only needs [start, start+deg) per node).
// ---------------------------------------------------------------------------
__global__ __launch_bounds__(256) void startcursor_kernel(
    const int* __restrict__ deg, int* __restrict__ gtotal,
    int* __restrict__ start, int* __restrict__ cursor)
{
    __shared__ int s[256];
    __shared__ int bbase;
    const int t = threadIdx.x;
    const int i = blockIdx.x * 256 + t;
    const int v = (i < N_NODES) ? deg[i] : 0;
    s[t] = v;
    __syncthreads();
    for (int d = 1; d < 256; d <<= 1) {
        const int u = (t >= d) ? s[t - d] : 0;
        __syncthreads();
        s[t] += u;
        __syncthreads();
    }
    if (t == 255) bbase = atomicAdd(gtotal, s[255]);
    __syncthreads();
    if (i < N_NODES) {
        const int ex = bbase + s[t] - v;
        start[i]  = ex;
        cursor[i] = ex;
    }
}

__global__ __launch_bounds__(256) void fill_kernel(
    const int* __restrict__ src, const int* __restrict__ dst,
    int* __restrict__ cursor, int* __restrict__ csr_src)
{
    const int e = blockIdx.x * 256 + threadIdx.x;
    if (e < N_EDGES) {
        const int pos = atomicAdd(&cursor[dst[e]], 1);
        csr_src[pos] = src[e];
    }
}

// ---------------------------------------------------------------------------
// Gather-aggregate + normalize + output GEMM, fused. One wave per dst node,
// EIGHT edges per iteration: lane = slot g (lane>>3) * 8 + sublane s (lane&7);
// sublane s holds cols 8s..8s+7 (head = s>>1). fp16 K/V: one dwordx4 per lane
// covers a full 8-col slice. 1-deep prefetch of the next 8-edge batch.
// ---------------------------------------------------------------------------
__global__ __launch_bounds__(256) void agg_kernel(
    const int* __restrict__ start, const int* __restrict__ deg,
    const int* __restrict__ csr_src,
    const float* __restrict__ Q, const __half* __restrict__ Kh,
    const __half* __restrict__ Vh,
    const float* __restrict__ ow, const float* __restrict__ ob,
    float* __restrict__ out)
{
    __shared__ float agg[4][64];
    const int wave = threadIdx.x >> 6;
    const int lane = threadIdx.x & 63;
    const int g    = lane >> 3;        // edge slot 0..7
    const int s    = lane & 7;         // sublane: cols 8s..8s+7
    const int node = blockIdx.x * 4 + wave;   // grid exact: 25000*4

    const float4* __restrict__ Q4 = (const float4*)Q;
    const uint4*  __restrict__ K4 = (const uint4*)Kh;  // 8 halves / uint4
    const uint4*  __restrict__ V4 = (const uint4*)Vh;

    const float4 qlo = Q4[(size_t)node * 16 + 2 * s];
    const float4 qhi = Q4[(size_t)node * 16 + 2 * s + 1];

    const int lo = start[node];
    const int hi = lo + deg[node];

    float acc[8] = {0.f, 0.f, 0.f, 0.f, 0.f, 0.f, 0.f, 0.f};
    float ssum = 0.f;

    if (lo < hi) {
        int base = lo;
        const int e0 = base + g;
        const int i0 = csr_src[(e0 < hi) ? e0 : (hi - 1)];
        bool act = (e0 < hi);
        uint4 ku = K4[(size_t)i0 * 8 + s];
        uint4 vu = V4[(size_t)i0 * 8 + s];

        while (base < hi) {
            const int nbase = base + 8;
            uint4 kn = make_uint4(0u, 0u, 0u, 0u);
            uint4 vn = make_uint4(0u, 0u, 0u, 0u);
            bool actn = false;
            if (nbase < hi) {                     // prefetch next 8-edge batch
                const int en = nbase + g;
                const int in_ = csr_src[(en < hi) ? en : (hi - 1)];
                kn = K4[(size_t)in_ * 8 + s];
                vn = V4[(size_t)in_ * 8 + s];
                actn = (en < hi);
            }
            // unpack fp16 -> f32
            float kf[8], vf[8];
            {
                const __half2* kh = (const __half2*)&ku;
                const __half2* vh = (const __half2*)&vu;
                #pragma unroll
                for (int j = 0; j < 4; ++j) {
                    const float2 a = __half22float2(kh[j]);
                    const float2 b = __half22float2(vh[j]);
                    kf[2 * j] = a.x; kf[2 * j + 1] = a.y;
                    vf[2 * j] = b.x; vf[2 * j + 1] = b.y;
                }
            }
            float d = qlo.x * kf[0] + qlo.y * kf[1] + qlo.z * kf[2] + qlo.w * kf[3]
                    + qhi.x * kf[4] + qhi.y * kf[5] + qhi.z * kf[6] + qhi.w * kf[7];
            d += __shfl_xor(d, 1);                // pair (s=2h, 2h+1): full head dot
            const float p = act ? __expf(d * 0.25f) : 0.f;   // 1/sqrt(16)
            ssum += p;
            #pragma unroll
            for (int j = 0; j < 8; ++j) acc[j] = fmaf(p, vf[j], acc[j]);
            ku = kn; vu = vn; act = actn; base = nbase;
        }
    }

    // combine the 8 edge slots (lane bits 3,4,5); ssum stays per-head
    #pragma unroll
    for (int m = 8; m <= 32; m <<= 1) {
        #pragma unroll
        for (int j = 0; j < 8; ++j) acc[j] += __shfl_xor(acc[j], m);
        ssum += __shfl_xor(ssum, m);
    }

    const float inv = (ssum > 0.f) ? (1.0f / ssum) : 0.0f;
    if (g == 0) {
        #pragma unroll
        for (int j = 0; j < 8; ++j) agg[wave][8 * s + j] = acc[j] * inv;
    }
    __syncthreads();

    float o = ob[lane];
    #pragma unroll 8
    for (int i = 0; i < 64; ++i)
        o = fmaf(agg[wave][i], ow[i * 64 + lane], o);
    out[(size_t)node * 64 + lane] = o;
}

// ---------------------------------------------------------------------------
extern "C" void kernel_launch(void* const* d_in, const int* in_sizes, int n_in,
                              void* d_out, int out_size, void* d_ws, size_t ws_size,
                              hipStream_t stream) {
    const float* x  = (const float*)d_in[0];
    const float* tf = (const float*)d_in[1];
    const int*   ei = (const int*)  d_in[2];
    const float* qw = (const float*)d_in[3];
    const float* qb = (const float*)d_in[4];
    const float* kw = (const float*)d_in[5];
    const float* kb = (const float*)d_in[6];
    const float* vw = (const float*)d_in[7];
    const float* vb = (const float*)d_in[8];
    const float* ow = (const float*)d_in[9];
    const float* ob = (const float*)d_in[10];
    float* out = (float*)d_out;

    char* ws = (char*)d_ws;
    const size_t qf = (size_t)N_NODES * 64 * sizeof(float);   // 25.6 MB
    const size_t hfsz = (size_t)N_NODES * 64 * sizeof(__half);// 12.8 MB

    float*  Q       = (float*)(ws);
    __half* Kh      = (__half*)(ws + qf);
    __half* Vh      = (__half*)(ws + qf + hfsz);
    int*    deg     = (int*)(ws + qf + 2 * hfsz);
    int*    gtotal  = deg + N_NODES;          // adjacent: one memset covers both
    int*    start   = gtotal + 1;
    int*    cursor  = start + N_NODES;
    int*    csr_src = cursor + N_NODES;

    const int* src = ei;             // edge_index[0]
    const int* dst = ei + N_EDGES;   // edge_index[1]

    hipMemsetAsync(deg, 0, (N_NODES + 1) * sizeof(int), stream);  // deg + gtotal

    const dim3 blk(256);
    qkv_deg_kernel<<<dim3(QKV_BLOCKS), blk, 0, stream>>>(
        x, tf, qw, qb, kw, kb, vw, vb, dst, deg, Q, Kh, Vh);

    startcursor_kernel<<<dim3(SC_BLOCKS), blk, 0, stream>>>(
        deg, gtotal, start, cursor);

    fill_kernel<<<dim3((N_EDGES + 255) / 256), blk, 0, stream>>>(
        src, dst, cursor, csr_src);

    agg_kernel<<<dim3(N_NODES / 4), blk, 0, stream>>>(
        start, deg, csr_src, Q, Kh, Vh, ow, ob, out);
}